// Round 12
// baseline (326.800 us; speedup 1.0000x reference)
//
#include <hip/hip_runtime.h>

#define LOG2E 1.4426950408889634f
#define LN2   0.6931471805599453f

typedef float f32x2 __attribute__((ext_vector_type(2)));

// r11 verified base (98 us, absmax 0): linear-domain fwd/bwd split,
//   alpha_t = D_t M alpha_{t-1},  beta_{t-1} = M^T (d_t beta_t),
// LDS uniform-address ds_read_b128 broadcast, v_pk_fma_f32 matvec,
// immediate integer-exponent rescale every 2 steps, join Z = beta_m^T alpha_m.
//
// Round-12 change: both chains of a batch now run in ONE wave (64-thread
// block), interleaved step-by-step. r11's step = 459 cyc ~= 130 VALU +
// ~330 serial DS (write->read RAW ~120, 16-read stream ~190, tail). The two
// chains are independent within a step, so chain B's DS stream and FMAs
// hide under chain A's fixed latencies and vice versa — fixed costs
// amortize over 2 chain-steps. No cross-wave sync anywhere (r1/r9 lesson:
// per-step __syncthreads is always a loss). Both M fragments (row i of M,
// col i of M) live in 128 pinned VGPRs (r2/r9 tripwire: VGPR_Count >= 180
// expected; a collapse to <100 means scratch).
#define STEP_BODY(MP, PB, B2, D, RESC) do {                                   \
    const float4* pb4_ = (const float4*)(PB);                                 \
    f32x2 a0_ = {0.f, 0.f}, a1_ = {0.f, 0.f}, a2_ = {0.f, 0.f},               \
          a3_ = {0.f, 0.f};                                                   \
    float p0ref_ = 0.f;                                                       \
    _Pragma("unroll")                                                         \
    for (int g = 0; g < 16; ++g) {                                            \
      float4 q_ = pb4_[g]; /* uniform addr -> ds_read_b128 broadcast */       \
      if (g == 0) p0ref_ = q_.x;                                              \
      f32x2 qlo_ = {q_.x, q_.y}, qhi_ = {q_.z, q_.w};                         \
      if ((g & 1) == 0) {                                                     \
        a0_ = __builtin_elementwise_fma(MP[2 * g + 0], qlo_, a0_);            \
        a1_ = __builtin_elementwise_fma(MP[2 * g + 1], qhi_, a1_);            \
      } else {                                                                \
        a2_ = __builtin_elementwise_fma(MP[2 * g + 0], qlo_, a2_);            \
        a3_ = __builtin_elementwise_fma(MP[2 * g + 1], qhi_, a3_);            \
      }                                                                       \
    }                                                                         \
    float mult_ = (D);                                                        \
    if (RESC) { /* anchor = replicated p[0] of the consumed state */          \
      unsigned bits_ = __float_as_uint(p0ref_);                               \
      int e_ = (int)((bits_ >> 23) & 0xffu);                                  \
      (B2) += e_ - 127;                                                       \
      mult_ *= __uint_as_float((unsigned)(254 - e_) << 23); /* 2^(127-e) */   \
    }                                                                         \
    f32x2 s01_ = a0_ + a1_, s23_ = a2_ + a3_; /* v_pk_add_f32 */              \
    f32x2 s2_ = s01_ + s23_;                                                  \
    (PB)[lane] = (s2_.x + s2_.y) * mult_; /* 2-way bank alias = free */       \
  } while (0)

__global__ __launch_bounds__(64)
__attribute__((amdgpu_waves_per_eu(1, 1)))
void crf_fwd_33852932227637(
    const float* __restrict__ h,
    const float* __restrict__ trans,
    const int* __restrict__ lengths,
    float* __restrict__ out,
    int T) {
  constexpr int N = 64;
  const int b = blockIdx.x;
  const int lane = threadIdx.x;

  const float* hb = h + (size_t)b * T * N;
  const int len = lengths[b];
  const int m = (len - 1) >> 1;   // join point
  const int nsF = m;              // fwd folded steps (t = 1..m)
  const int nsB = len - 1 - m;    // bwd matvec count (t = len-1..m+1)
  const int nsBf = nsB - 1;       // bwd folded steps (final one is raw)

  // M fragments, packed pairs: MpF = row `lane` of M = exp(trans);
  // MpB = column `lane` (row of M^T). Prologue-only, L2-resident.
  f32x2 MpF[32], MpB[32];
  {
    const float4* trow = (const float4*)(trans + lane * N);
#pragma unroll
    for (int q = 0; q < 16; ++q) {
      float4 tq = trow[q];
      MpF[2 * q + 0] = {__builtin_amdgcn_exp2f(tq.x * LOG2E),
                        __builtin_amdgcn_exp2f(tq.y * LOG2E)};
      MpF[2 * q + 1] = {__builtin_amdgcn_exp2f(tq.z * LOG2E),
                        __builtin_amdgcn_exp2f(tq.w * LOG2E)};
    }
#pragma unroll
    for (int q = 0; q < 32; ++q) {
      MpB[q] = {__builtin_amdgcn_exp2f(trans[(2 * q + 0) * N + lane] * LOG2E),
                __builtin_amdgcn_exp2f(trans[(2 * q + 1) * N + lane] * LOG2E)};
    }
  }
  // Pin both into arch VGPR pairs (r2/r9: otherwise AGPR/scratch parking).
#pragma unroll
  for (int q = 0; q < 8; ++q) {
    asm volatile("" : "+v"(MpF[4 * q + 0]), "+v"(MpF[4 * q + 1]),
                      "+v"(MpF[4 * q + 2]), "+v"(MpF[4 * q + 3]));
  }
#pragma unroll
  for (int q = 0; q < 8; ++q) {
    asm volatile("" : "+v"(MpB[4 * q + 0]), "+v"(MpB[4 * q + 1]),
                      "+v"(MpB[4 * q + 2]), "+v"(MpB[4 * q + 3]));
  }

  // State buffers (one per chain); same wave owns both -> in-order DS, no
  // barriers. Init: alpha_0[i] = exp(h[0,i]+trans[i,START]); beta side =
  // u_END[i] = exp(trans[END,i]) with d_{len-1} folded when a matvec exists.
  __shared__ __align__(16) float pbuf[2][N];
  pbuf[0][lane] =
      __builtin_amdgcn_exp2f((hb[lane] + trans[lane * N + (N - 2)]) * LOG2E);
  {
    float v = __builtin_amdgcn_exp2f(trans[(N - 1) * N + lane] * LOG2E);
    if (nsB >= 1)
      v *= __builtin_amdgcn_exp2f(hb[(size_t)(len - 1) * N + lane] * LOG2E);
    pbuf[1][lane] = v;
  }
  int b2F = 0, b2B = 0;

  // Emissions for folded step s: fwd consumes d_s; bwd consumes d_{len-1-s}.
  // Clamped addresses (value unused when clamped; address stays in range).
  auto emitF = [&](int s_) -> float {
    int smax = nsF < 1 ? 1 : nsF;
    int sc2 = s_ < smax ? s_ : smax;
    if (sc2 < 1) sc2 = 1;
    return __builtin_amdgcn_exp2f(hb[(size_t)sc2 * N + lane] * LOG2E);
  };
  auto emitB = [&](int s_) -> float {
    int smax = nsBf < 1 ? 1 : nsBf;
    int sc2 = s_ < smax ? s_ : smax;
    if (sc2 < 1) sc2 = 1;
    int t = len - 1 - sc2;
    if (t < 0) t = 0;
    return __builtin_amdgcn_exp2f(hb[(size_t)t * N + lane] * LOG2E);
  };

  // Interleaved main loop over sc = min(nsF, nsBf) double-steps.
  // (len-1 even: nsBf = nsF-1 -> one fwd leftover; odd: nsBf = nsF.)
  const int sc = nsF < nsBf ? nsF : nsBf;
  float ebF[4], ebB[4];
#pragma unroll
  for (int u = 0; u < 4; ++u) {
    ebF[u] = emitF(1 + u);
    ebB[u] = emitB(1 + u);
  }

  int s = 1;
  for (; s + 4 <= sc + 1; s += 4) {
#pragma unroll
    for (int u = 0; u < 4; ++u) {
      STEP_BODY(MpF, pbuf[0], b2F, ebF[u], (u & 1) == 1);
      STEP_BODY(MpB, pbuf[1], b2B, ebB[u], (u & 1) == 1);
      ebF[u] = emitF(s + u + 4);
      ebB[u] = emitB(s + u + 4);
    }
  }
  for (; s <= sc; ++s) {  // <=3 leftover double-steps; slot (s-1)&3 holds d_s
    STEP_BODY(MpF, pbuf[0], b2F, ebF[(s - 1) & 3], true);
    STEP_BODY(MpB, pbuf[1], b2B, ebB[(s - 1) & 3], true);
  }
  // Fwd leftover (only when len-1 is even and nsF >= 1): step s2 = nsF.
  for (int s2 = (sc + 1 < 1 ? 1 : sc + 1); s2 <= nsF; ++s2)
    STEP_BODY(MpF, pbuf[0], b2F, ebF[(s2 - 1) & 3], true);
  // Final raw bwd step (beta_m excludes d_m).
  if (nsB >= 1) STEP_BODY(MpB, pbuf[1], b2B, 1.0f, true);

  // Join in-wave: Z * 2^-(b2F+b2B) = sum_i alpha_m[i] * beta_m[i]; anchors
  // keep both factors ~2^0, so the dot neither over- nor underflows.
  float z = pbuf[0][lane] * pbuf[1][lane];
#pragma unroll
  for (int off = 32; off >= 1; off >>= 1)
    z += __shfl_xor(z, off, 64);
  if (lane == 0)
    out[b] = LN2 * ((float)(b2F + b2B) + __builtin_amdgcn_logf(z));
}

extern "C" void kernel_launch(void* const* d_in, const int* in_sizes, int n_in,
                              void* d_out, int out_size, void* d_ws, size_t ws_size,
                              hipStream_t stream) {
  const float* h = (const float*)d_in[0];
  const float* trans = (const float*)d_in[1];
  const int* lengths = (const int*)d_in[2];
  float* out = (float*)d_out;
  const int B = in_sizes[2];
  const int N = 64;
  const int T = in_sizes[0] / (B * N);
  crf_fwd_33852932227637<<<B, N, 0, stream>>>(h, trans, lengths, out, T);
}

// Round 14
// 248.501 us; speedup vs baseline: 1.3151x; 1.3151x over previous
//
#include <hip/hip_runtime.h>

#define LOG2E 1.4426950408889634f
#define LN2   0.6931471805599453f

typedef float f32x2 __attribute__((ext_vector_type(2)));

// r11 verified base (98 us, absmax 0): linear-domain fwd/bwd split,
//   alpha_t = D_t M alpha_{t-1},  beta_{t-1} = M^T (d_t beta_t),
// one wave per chain, LDS uniform-address broadcast, v_pk_fma_f32 matvec,
// immediate integer-exponent rescale every 2 steps, join Z = beta_m^T alpha_m.
//
// Round-14: corrected i/j pair-split. r13's bug: 32 lane-pairs can't own 64
// states — states 32..63 were never written (absmax 672). Fix: pair (2k,2k+1)
// owns TWO states, k and k+32. Per lane: jh=lane&1 selects the 32-wide
// j-half; 8 uniform-pair ds_read_b128 feed BOTH states' FMAs (32 pk_fma —
// same FMA count as r11; the DS read stream is what halves: 17 -> ~10.5
// DS ops/step). Pair-combine = one quad_perm xor-1 DPP + add per state
// (single op, same quad — not r8's dependent walk). Writes: 2 per lane,
// each address written by both pair-lanes with the identical value (benign).
// M footprint: 2 x 16 f32x2 = 64 VGPRs — at r11's level, below the ~132
// allocator cliff (r12 lesson). No cross-wave sync (r1/r9/r12 lesson).
__device__ __forceinline__ float dpp_xor1(float v) {
  // quad_perm [1,0,3,2]: swap within lane pairs; self-inverse.
  return __int_as_float(
      __builtin_amdgcn_mov_dpp(__float_as_int(v), 0xB1, 0xf, 0xf, true));
}

template <bool FWD>
__device__ __forceinline__ void run_chain(
    const float* __restrict__ hb, const float* __restrict__ trans,
    float* __restrict__ pbuf, int lane, int len, int nsteps, int& b2Out) {
  constexpr int N = 64;
  const int k = lane >> 1;   // first owned state (second is k+32)
  const int jh = lane & 1;   // j-half this lane reduces (cols 32jh..32jh+31)

  // M fragments, 16 packed pairs each. FWD: MpA = M[k][32jh..32jh+31],
  // MpB = M[k+32][32jh..]; M = exp(trans). BWD: rows of M^T instead:
  // MpA[q] = trans[32jh+2q][k], MpB[q] = trans[32jh+2q][k+32].
  f32x2 MpA[16], MpB[16];
  if (FWD) {
    const float4* trA = (const float4*)(trans + k * N + 32 * jh);
    const float4* trB = (const float4*)(trans + (k + 32) * N + 32 * jh);
#pragma unroll
    for (int q = 0; q < 8; ++q) {
      float4 ta = trA[q];
      MpA[2 * q + 0] = {__builtin_amdgcn_exp2f(ta.x * LOG2E),
                        __builtin_amdgcn_exp2f(ta.y * LOG2E)};
      MpA[2 * q + 1] = {__builtin_amdgcn_exp2f(ta.z * LOG2E),
                        __builtin_amdgcn_exp2f(ta.w * LOG2E)};
      float4 tb = trB[q];
      MpB[2 * q + 0] = {__builtin_amdgcn_exp2f(tb.x * LOG2E),
                        __builtin_amdgcn_exp2f(tb.y * LOG2E)};
      MpB[2 * q + 1] = {__builtin_amdgcn_exp2f(tb.z * LOG2E),
                        __builtin_amdgcn_exp2f(tb.w * LOG2E)};
    }
  } else {
#pragma unroll
    for (int q = 0; q < 16; ++q) {
      int j0 = 32 * jh + 2 * q, j1 = j0 + 1;
      MpA[q] = {__builtin_amdgcn_exp2f(trans[j0 * N + k] * LOG2E),
                __builtin_amdgcn_exp2f(trans[j1 * N + k] * LOG2E)};
      MpB[q] = {__builtin_amdgcn_exp2f(trans[j0 * N + (k + 32)] * LOG2E),
                __builtin_amdgcn_exp2f(trans[j1 * N + (k + 32)] * LOG2E)};
    }
  }
  // Pin into arch VGPR pairs (r2/r9/r12 tripwire: VGPR_Count in counters).
#pragma unroll
  for (int q = 0; q < 4; ++q) {
    asm volatile("" : "+v"(MpA[4 * q + 0]), "+v"(MpA[4 * q + 1]),
                      "+v"(MpA[4 * q + 2]), "+v"(MpA[4 * q + 3]));
    asm volatile("" : "+v"(MpB[4 * q + 0]), "+v"(MpB[4 * q + 1]),
                      "+v"(MpB[4 * q + 2]), "+v"(MpB[4 * q + 3]));
  }

  // Init state in LDS (full-lane: lane writes state `lane` — all 64 states).
  // FWD: alpha_0[i] = exp(h[0,i]+trans[i,START]); BWD: u_END[i] =
  // exp(trans[END,i]), folding d_{len-1} when a matvec exists. START=N-2.
  {
    float v;
    if (FWD) {
      v = __builtin_amdgcn_exp2f((hb[lane] + trans[lane * N + (N - 2)]) * LOG2E);
    } else {
      v = __builtin_amdgcn_exp2f(trans[(N - 1) * N + lane] * LOG2E);
      if (nsteps >= 1)
        v *= __builtin_amdgcn_exp2f(hb[(size_t)(len - 1) * N + lane] * LOG2E);
    }
    pbuf[lane] = v;
  }
  int base2 = 0;

  // Folded-step count: FWD all nsteps (D after matvec); BWD nsteps-1 folded
  // + one final RAW step (beta_m excludes d_m).
  const int ns = FWD ? nsteps : nsteps - 1;

  const float4* pb4 = (const float4*)pbuf + 8 * jh;  // this lane's j-half

  auto step = [&](float DA, float DB, bool resc) {
    float mult = 1.0f;
    if (resc) {  // anchor = replicated p[0] of the consumed state (uniform)
      float anch = pbuf[0];
      unsigned bits = __float_as_uint(anch);
      int e = (int)((bits >> 23) & 0xffu);
      base2 += e - 127;
      mult = __uint_as_float((unsigned)(254 - e) << 23);  // 2^(127-e)
    }
    f32x2 a0 = {0.f, 0.f}, a1 = {0.f, 0.f};
    f32x2 b0 = {0.f, 0.f}, b1 = {0.f, 0.f};
#pragma unroll
    for (int g = 0; g < 8; ++g) {
      float4 q = pb4[g];  // 2 distinct addrs across wave -> free broadcast
      f32x2 qlo = {q.x, q.y}, qhi = {q.z, q.w};
      a0 = __builtin_elementwise_fma(MpA[2 * g + 0], qlo, a0);
      a1 = __builtin_elementwise_fma(MpA[2 * g + 1], qhi, a1);
      b0 = __builtin_elementwise_fma(MpB[2 * g + 0], qlo, b0);
      b1 = __builtin_elementwise_fma(MpB[2 * g + 1], qhi, b1);
    }
    f32x2 sa = a0 + a1;                   // v_pk_add_f32
    float pa = sa.x + sa.y;               // this lane's 32-term half (state k)
    float sumA = pa + dpp_xor1(pa);       // pair combine: full 64-term dot
    f32x2 sb = b0 + b1;
    float pb = sb.x + sb.y;               // half for state k+32
    float sumB = pb + dpp_xor1(pb);
    pbuf[k]      = sumA * (DA * mult);    // pair-lanes: same addr, same value
    pbuf[k + 32] = sumB * (DB * mult);
  };

  // Emission for folded step s of given state: FWD t=s; BWD t=len-1-s.
  auto emit_of = [&](int s_, int state) -> float {
    int smax = ns < 1 ? 1 : ns;
    int sc = s_ < smax ? s_ : smax;
    if (sc < 1) sc = 1;
    int t = FWD ? sc : (len - 1 - sc);
    if (t < 0) t = 0;  // value unused when clamped; address stays in range
    return __builtin_amdgcn_exp2f(hb[(size_t)t * N + state] * LOG2E);
  };

  float ebA[4], ebB[4];
#pragma unroll
  for (int u = 0; u < 4; ++u) {
    ebA[u] = emit_of(1 + u, k);
    ebB[u] = emit_of(1 + u, k + 32);
  }

  int s = 1;
  for (; s + 4 <= ns + 1; s += 4) {
#pragma unroll
    for (int u = 0; u < 4; ++u) {
      step(ebA[u], ebB[u], (u & 1) == 1);  // rescale every 2 steps
      ebA[u] = emit_of(s + u + 4, k);
      ebB[u] = emit_of(s + u + 4, k + 32);
    }
  }
  for (; s <= ns; ++s)  // tail: slot (s-1)&3 (loop exits s == 1 mod 4)
    step(ebA[(s - 1) & 3], ebB[(s - 1) & 3], true);
  if (!FWD && nsteps >= 1) step(1.0f, 1.0f, true);  // final raw beta_m step

  b2Out = base2;
}

__global__ __launch_bounds__(128)
__attribute__((amdgpu_waves_per_eu(1, 1)))
void crf_fwd_33852932227637(
    const float* __restrict__ h,
    const float* __restrict__ trans,
    const int* __restrict__ lengths,
    float* __restrict__ out,
    int T) {
  constexpr int N = 64;
  const int b = blockIdx.x;
  const int lane = threadIdx.x & 63;
  const int wv = threadIdx.x >> 6;

  const float* hb = h + (size_t)b * T * N;
  const int len = lengths[b];
  const int m = (len - 1) >> 1;  // fwd matvecs: 1..m ; bwd matvecs: len-1..m+1

  __shared__ __align__(16) float pbuf[2][N];
  __shared__ int xb2[2];

  int b2;
  if (wv == 0)
    run_chain<true>(hb, trans, pbuf[0], lane, len, m, b2);
  else
    run_chain<false>(hb, trans, pbuf[1], lane, len, len - 1 - m, b2);
  if (lane == 0) xb2[wv] = b2;
  __syncthreads();

  if (wv == 0) {
    // Z * 2^-(b2f+b2b) = sum_i alpha_m[i] * beta_m[i]; anchors keep both
    // factors ~2^0, so the dot neither over- nor underflows.
    float z = pbuf[0][lane] * pbuf[1][lane];
#pragma unroll
    for (int off = 32; off >= 1; off >>= 1)
      z += __shfl_xor(z, off, 64);
    if (lane == 0)
      out[b] = LN2 * ((float)(xb2[0] + xb2[1]) + __builtin_amdgcn_logf(z));
  }
}

extern "C" void kernel_launch(void* const* d_in, const int* in_sizes, int n_in,
                              void* d_out, int out_size, void* d_ws, size_t ws_size,
                              hipStream_t stream) {
  const float* h = (const float*)d_in[0];
  const float* trans = (const float*)d_in[1];
  const int* lengths = (const int*)d_in[2];
  float* out = (float*)d_out;
  const int B = in_sizes[2];
  const int N = 64;
  const int T = in_sizes[0] / (B * N);
  crf_fwd_33852932227637<<<B, N * 2, 0, stream>>>(h, trans, lengths, out, T);
}